// Round 3
// baseline (269.934 us; speedup 1.0000x reference)
//
#include <hip/hip_runtime.h>
#include <hip/hip_bf16.h>

#define SEQ 2048
#define BATCH 2
#define IN_DIM 512
#define EMBED 512
#define HEADS 8
#define HD 64
#define N3 1536

using f32x4 = __attribute__((ext_vector_type(4))) float;
using s16x8 = __attribute__((ext_vector_type(8))) short;

__device__ __forceinline__ unsigned short f2bf(float f) {
    union { float f; unsigned int u; } v; v.f = f;
    unsigned int u = v.u;
    unsigned int r = (u + 0x7FFFu + ((u >> 16) & 1u)) >> 16;
    return (unsigned short)r;
}

__device__ __forceinline__ void async16(void* lds, const void* g) {
    __builtin_amdgcn_global_load_lds(
        (const __attribute__((address_space(1))) unsigned int*)g,
        (__attribute__((address_space(3))) unsigned int*)lds, 16, 0, 0);
}

// ---------- prep: x [S][B][D] fp32 -> Ab [B*S][D] bf16 ----------
__global__ __launch_bounds__(256) void prep_x(
    const float* __restrict__ x, unsigned short* __restrict__ Ab)
{
    const int gid = blockIdx.x * 256 + threadIdx.x;
    const int base = gid * 4;
    const int m = base >> 9, k = base & 511;
    const int b = m >> 11, s = m & 2047;
    float4 f = *reinterpret_cast<const float4*>(x + ((size_t)s * BATCH + b) * IN_DIM + k);
    ushort4 u;
    u.x = f2bf(f.x); u.y = f2bf(f.y); u.z = f2bf(f.z); u.w = f2bf(f.w);
    *reinterpret_cast<ushort4*>(Ab + (size_t)m * IN_DIM + k) = u;
}

// ---------- prep: both weight transposes fp32 [K][N] -> bf16 [N][K] ----------
__global__ __launch_bounds__(256) void transpose_w2(
    const float* __restrict__ Wqkv, const float* __restrict__ Wo,
    unsigned short* __restrict__ Wqkvt, unsigned short* __restrict__ Wot)
{
    __shared__ __align__(16) unsigned short T[64][72];
    const int yy = blockIdx.y;
    const float* in; unsigned short* out; int N, n0;
    if (yy < 24) { in = Wqkv; out = Wqkvt; N = N3;    n0 = yy * 64; }
    else         { in = Wo;   out = Wot;   N = EMBED; n0 = (yy - 24) * 64; }
    const int k0 = blockIdx.x * 64;
    const int tid = threadIdx.x;
    const int ri = tid >> 2, cj = (tid & 3) * 16;
#pragma unroll
    for (int v = 0; v < 4; v++) {
        float4 f = *reinterpret_cast<const float4*>(in + (size_t)(k0 + ri) * N + n0 + cj + 4 * v);
        T[cj + 4 * v + 0][ri] = f2bf(f.x);
        T[cj + 4 * v + 1][ri] = f2bf(f.y);
        T[cj + 4 * v + 2][ri] = f2bf(f.z);
        T[cj + 4 * v + 3][ri] = f2bf(f.w);
    }
    __syncthreads();
    unsigned short* dst = out + (size_t)(n0 + ri) * IN_DIM + k0 + cj;
    *reinterpret_cast<uint4*>(dst)     = *reinterpret_cast<const uint4*>(&T[ri][cj]);
    *reinterpret_cast<uint4*>(dst + 8) = *reinterpret_cast<const uint4*>(&T[ri][cj + 8]);
}

// ---------------- Kernel 1: QKV projection GEMM (m97-style) ----------------
// BM=64, BN=128, BK=64. gload_lds(16B) + T2 XOR swizzle. grid (64, 12).
__global__ __launch_bounds__(256) void qkv_gemm(
    const unsigned short* __restrict__ Ab, const unsigned short* __restrict__ Wt,
    const float* __restrict__ bqkv,
    unsigned short* __restrict__ Qb, unsigned short* __restrict__ Kb,
    unsigned short* __restrict__ Vt)
{
    __shared__ __align__(16) unsigned short As[64 * 64];
    __shared__ __align__(16) unsigned short Bs[128 * 64];
    const int tid = threadIdx.x, lane = tid & 63, w = tid >> 6;
    const int fr = lane & 15, fg = lane >> 4;
    const int m0 = blockIdx.x * 64, n0 = blockIdx.y * 128;
    const int sr = lane >> 3;           // row within wave's 8-row stage group
    const int scs = ((lane & 7) * 16) ^ (sr << 4);  // swizzled source byte col

    const unsigned char* Ag = (const unsigned char*)Ab + (size_t)(m0 + w * 8 + sr) * 1024 + scs;
    const unsigned char* Bg = (const unsigned char*)Wt + (size_t)(n0 + w * 8 + sr) * 1024 + scs;
    unsigned char* Asb = (unsigned char*)As;
    unsigned char* Bsb = (unsigned char*)Bs;

    f32x4 acc[2][4];
#pragma unroll
    for (int mt = 0; mt < 2; mt++)
#pragma unroll
        for (int nt = 0; nt < 4; nt++) acc[mt][nt] = (f32x4){0.f, 0.f, 0.f, 0.f};

    const int swz = (fr & 7) << 4;

    for (int k0 = 0; k0 < IN_DIM; k0 += 64) {
        async16(Asb + (w * 8) * 128,        Ag);
        async16(Asb + (32 + w * 8) * 128,   Ag + (size_t)32 * 1024);
        async16(Bsb + (w * 8) * 128,        Bg);
        async16(Bsb + (32 + w * 8) * 128,   Bg + (size_t)32 * 1024);
        async16(Bsb + (64 + w * 8) * 128,   Bg + (size_t)64 * 1024);
        async16(Bsb + (96 + w * 8) * 128,   Bg + (size_t)96 * 1024);
        Ag += 128; Bg += 128;
        __syncthreads();
#pragma unroll
        for (int h2 = 0; h2 < 2; h2++) {
            const int cb = (h2 * 64 + fg * 16) ^ swz;
            s16x8 a[2], bf[4];
#pragma unroll
            for (int mt = 0; mt < 2; mt++) {
                const int row = (w >> 1) * 32 + mt * 16 + fr;
                a[mt] = *reinterpret_cast<const s16x8*>(Asb + row * 128 + cb);
            }
#pragma unroll
            for (int nt = 0; nt < 4; nt++) {
                const int nrow = (w & 1) * 64 + nt * 16 + fr;
                bf[nt] = *reinterpret_cast<const s16x8*>(Bsb + nrow * 128 + cb);
            }
#pragma unroll
            for (int mt = 0; mt < 2; mt++)
#pragma unroll
                for (int nt = 0; nt < 4; nt++)
                    acc[mt][nt] = __builtin_amdgcn_mfma_f32_16x16x32_bf16(a[mt], bf[nt], acc[mt][nt], 0, 0, 0);
        }
        __syncthreads();
    }

    // epilogue: route per 16-col fragment (uniform per (wave, nt))
    const int wc = w & 1, wr = w >> 1;
    const int b_ = m0 >> 11;
    const int sB = (m0 & 2047) + wr * 32;
#pragma unroll
    for (int nt = 0; nt < 4; nt++) {
        const int col0 = n0 + wc * 64 + nt * 16;
        const int g = col0 >> 6;
        const int hh = g / 3, part = g % 3;
        const int d = (col0 & 63) + fr;
        const float bq = bqkv[col0 + fr];
        if (part < 2) {
            unsigned short* dst = (part == 0 ? Qb : Kb) + ((size_t)b_ * HEADS + hh) * SEQ * HD;
#pragma unroll
            for (int mt = 0; mt < 2; mt++)
#pragma unroll
                for (int j = 0; j < 4; j++) {
                    const int s = sB + mt * 16 + fg * 4 + j;
                    dst[(size_t)s * HD + d] = f2bf(acc[mt][nt][j] + bq);
                }
        } else {
            unsigned short* dst = Vt + (((size_t)b_ * HEADS + hh) * HD + d) * SEQ;
#pragma unroll
            for (int mt = 0; mt < 2; mt++) {
                ushort4 u;
                u.x = f2bf(acc[mt][nt][0] + bq);
                u.y = f2bf(acc[mt][nt][1] + bq);
                u.z = f2bf(acc[mt][nt][2] + bq);
                u.w = f2bf(acc[mt][nt][3] + bq);
                *reinterpret_cast<ushort4*>(&dst[sB + mt * 16 + fg * 4]) = u;
            }
        }
    }
}

// ---------------- Kernel 2: flash attention, swapped QK^T, optional split-K ----------------
// grid (32, 8, 2*NSPL). Wave w owns q rows [q0+16w, q0+16w+16); per-lane q = q0+16w+fr.
template<int NSPL>
__global__ __launch_bounds__(256) void flash_attn(
    const unsigned short* __restrict__ Qb, const unsigned short* __restrict__ Kb,
    const unsigned short* __restrict__ Vt, const float* __restrict__ bias,
    unsigned short* __restrict__ Ob, float* __restrict__ Opart,
    float* __restrict__ Mpart, float* __restrict__ Lpart)
{
    __shared__ __align__(16) unsigned short Ks[2][64][72];
    __shared__ __align__(16) unsigned short Vs[2][64][72];   // [d][key]
    __shared__ __align__(16) unsigned short Ps[4][16][72];   // per-wave P[q][k]
    const int h = blockIdx.y;
    const int z = blockIdx.z;
    const int b  = (NSPL == 2) ? (z >> 1) : z;
    const int sp = (NSPL == 2) ? (z & 1) : 0;
    const int NST = (NSPL == 2) ? 16 : 32;
    const int kst = sp * (SEQ / NSPL);
    const int q0 = blockIdx.x * 64;
    const int tid = threadIdx.x, lane = tid & 63, w = tid >> 6;
    const int fr = lane & 15, fg = lane >> 4;

    const unsigned short* Kbase = Kb + (size_t)(b * HEADS + h) * SEQ * HD;
    const unsigned short* Vbase = Vt + (size_t)(b * HEADS + h) * HD * SEQ;
    const float* bbase = bias + (size_t)h * SEQ * SEQ + (size_t)q0 * SEQ;

    // Q fragments: B-operand (n=q), per-lane q = q0+16w+fr
    const unsigned short* qrow = Qb + ((size_t)(b * HEADS + h) * SEQ + q0 + w * 16 + fr) * HD;
    s16x8 qf0 = *reinterpret_cast<const s16x8*>(qrow + fg * 8);
    s16x8 qf1 = *reinterpret_cast<const s16x8*>(qrow + 32 + fg * 8);

    const int r0 = tid >> 3, c0 = (tid & 7) * 8;
    const int r1 = r0 + 32;

    uint4 kr0, kr1, vr0, vr1;
    f32x4 bA[4], bB[4];
    const float* brow = bbase + (size_t)(w * 16 + fr) * SEQ;

    // prologue: tile 0 of this split
    kr0 = *reinterpret_cast<const uint4*>(Kbase + (size_t)(kst + r0) * HD + c0);
    kr1 = *reinterpret_cast<const uint4*>(Kbase + (size_t)(kst + r1) * HD + c0);
    vr0 = *reinterpret_cast<const uint4*>(Vbase + (size_t)r0 * SEQ + kst + c0);
    vr1 = *reinterpret_cast<const uint4*>(Vbase + (size_t)r1 * SEQ + kst + c0);
#pragma unroll
    for (int t = 0; t < 4; t++)
        bA[t] = *reinterpret_cast<const f32x4*>(brow + kst + t * 16 + fg * 4);
    *reinterpret_cast<uint4*>(&Ks[0][r0][c0]) = kr0;
    *reinterpret_cast<uint4*>(&Ks[0][r1][c0]) = kr1;
    *reinterpret_cast<uint4*>(&Vs[0][r0][c0]) = vr0;
    *reinterpret_cast<uint4*>(&Vs[0][r1][c0]) = vr1;
    __syncthreads();

    float mrow = -1e30f, lrow = 0.f;
    f32x4 oacc[4];
#pragma unroll
    for (int t = 0; t < 4; t++) oacc[t] = (f32x4){0.f, 0.f, 0.f, 0.f};

    const float scale = 0.08838834764831845f; // 1/sqrt(2*64)

    auto body = [&](int n, const f32x4 (&bc)[4], f32x4 (&bnx)[4]) {
        const int cur = n & 1;
        const bool pf = (n < NST - 1);
        const int kn = kst + (n + 1) * 64;
        if (pf) {
            kr0 = *reinterpret_cast<const uint4*>(Kbase + (size_t)(kn + r0) * HD + c0);
            kr1 = *reinterpret_cast<const uint4*>(Kbase + (size_t)(kn + r1) * HD + c0);
            vr0 = *reinterpret_cast<const uint4*>(Vbase + (size_t)r0 * SEQ + kn + c0);
            vr1 = *reinterpret_cast<const uint4*>(Vbase + (size_t)r1 * SEQ + kn + c0);
#pragma unroll
            for (int t = 0; t < 4; t++)
                bnx[t] = *reinterpret_cast<const f32x4*>(brow + kn + t * 16 + fg * 4);
        }
        // S^T = K Q^T : per-lane holds 16 k-values for q = q0+16w+fr
        f32x4 p[4];
#pragma unroll
        for (int t = 0; t < 4; t++) p[t] = (f32x4){0.f, 0.f, 0.f, 0.f};
#pragma unroll
        for (int h2 = 0; h2 < 2; h2++) {
            s16x8 qf = (h2 == 0) ? qf0 : qf1;
#pragma unroll
            for (int t = 0; t < 4; t++) {
                s16x8 kf = *reinterpret_cast<const s16x8*>(&Ks[cur][t * 16 + fr][h2 * 32 + fg * 8]);
                p[t] = __builtin_amdgcn_mfma_f32_16x16x32_bf16(kf, qf, p[t], 0, 0, 0);
            }
        }
#pragma unroll
        for (int t = 0; t < 4; t++)
#pragma unroll
            for (int j = 0; j < 4; j++)
                p[t][j] = p[t][j] * scale + bc[t][j];
        // lane-local max over 16, then across 4 fg replicas
        float tm = fmaxf(fmaxf(fmaxf(p[0][0], p[0][1]), fmaxf(p[0][2], p[0][3])),
                         fmaxf(fmaxf(p[1][0], p[1][1]), fmaxf(p[1][2], p[1][3])));
        tm = fmaxf(tm, fmaxf(fmaxf(fmaxf(p[2][0], p[2][1]), fmaxf(p[2][2], p[2][3])),
                             fmaxf(fmaxf(p[3][0], p[3][1]), fmaxf(p[3][2], p[3][3]))));
        tm = fmaxf(tm, __shfl_xor(tm, 16, 64));
        tm = fmaxf(tm, __shfl_xor(tm, 32, 64));
        const float newm = fmaxf(mrow, tm);
        const float fac = __expf(mrow - newm);
        mrow = newm;
#pragma unroll
        for (int t = 0; t < 4; t++)
#pragma unroll
            for (int j = 0; j < 4; j++)
                p[t][j] = __expf(p[t][j] - mrow);
        float ts = (p[0][0] + p[0][1] + p[0][2] + p[0][3]) + (p[1][0] + p[1][1] + p[1][2] + p[1][3])
                 + (p[2][0] + p[2][1] + p[2][2] + p[2][3]) + (p[3][0] + p[3][1] + p[3][2] + p[3][3]);
        ts += __shfl_xor(ts, 16, 64);
        ts += __shfl_xor(ts, 32, 64);
        lrow = lrow * fac + ts;
        // P -> per-wave LDS [q][k], ushort4 per t
#pragma unroll
        for (int t = 0; t < 4; t++) {
            ushort4 u;
            u.x = f2bf(p[t][0]); u.y = f2bf(p[t][1]); u.z = f2bf(p[t][2]); u.w = f2bf(p[t][3]);
            *reinterpret_cast<ushort4*>(&Ps[w][fr][t * 16 + fg * 4]) = u;
        }
#pragma unroll
        for (int t = 0; t < 4; t++)
#pragma unroll
            for (int j = 0; j < 4; j++)
                oacc[t][j] *= fac;
        // O^T += V^T P^T  (A = V^T rows d, B = P rows q)
#pragma unroll
        for (int h2 = 0; h2 < 2; h2++) {
            s16x8 pa = *reinterpret_cast<const s16x8*>(&Ps[w][fr][h2 * 32 + fg * 8]);
#pragma unroll
            for (int t = 0; t < 4; t++) {
                s16x8 vf = *reinterpret_cast<const s16x8*>(&Vs[cur][t * 16 + fr][h2 * 32 + fg * 8]);
                oacc[t] = __builtin_amdgcn_mfma_f32_16x16x32_bf16(vf, pa, oacc[t], 0, 0, 0);
            }
        }
        if (pf) {
            const int nxt = cur ^ 1;
            *reinterpret_cast<uint4*>(&Ks[nxt][r0][c0]) = kr0;
            *reinterpret_cast<uint4*>(&Ks[nxt][r1][c0]) = kr1;
            *reinterpret_cast<uint4*>(&Vs[nxt][r0][c0]) = vr0;
            *reinterpret_cast<uint4*>(&Vs[nxt][r1][c0]) = vr1;
        }
        __syncthreads();
    };

    for (int n = 0; n < NST; n += 2) {
        body(n, bA, bB);
        body(n + 1, bB, bA);
    }

    if (NSPL == 1) {
        const float inv = 1.f / lrow;
        unsigned short* dst = Ob + ((size_t)b * SEQ + q0 + w * 16 + fr) * EMBED + h * HD;
#pragma unroll
        for (int t = 0; t < 4; t++) {
            ushort4 u;
            u.x = f2bf(oacc[t][0] * inv); u.y = f2bf(oacc[t][1] * inv);
            u.z = f2bf(oacc[t][2] * inv); u.w = f2bf(oacc[t][3] * inv);
            *reinterpret_cast<ushort4*>(dst + t * 16 + fg * 4) = u;
        }
    } else {
        const int tile = (z * HEADS + h) * 32 + blockIdx.x;
        float* Op = Opart + (size_t)tile * 4096 + (w * 16 + fr) * 64;
#pragma unroll
        for (int t = 0; t < 4; t++)
            *reinterpret_cast<f32x4*>(Op + t * 16 + fg * 4) = oacc[t];
        if (fg == 0) {
            Mpart[tile * 64 + w * 16 + fr] = mrow;
            Lpart[tile * 64 + w * 16 + fr] = lrow;
        }
    }
}

// ---------------- combine split-K partials ----------------
__global__ __launch_bounds__(256) void combine(
    const float* __restrict__ Opart, const float* __restrict__ Mpart,
    const float* __restrict__ Lpart, unsigned short* __restrict__ Ob)
{
    const int qt = blockIdx.x, h = blockIdx.y, b = blockIdx.z;
    const int t = threadIdx.x;
    const int q = t >> 2, dc = (t & 3) * 16;
    const int t0 = ((b * 2 + 0) * HEADS + h) * 32 + qt;
    const int t1 = ((b * 2 + 1) * HEADS + h) * 32 + qt;
    const float m1 = Mpart[t0 * 64 + q], l1 = Lpart[t0 * 64 + q];
    const float m2 = Mpart[t1 * 64 + q], l2 = Lpart[t1 * 64 + q];
    const float M = fmaxf(m1, m2);
    const float w1 = __expf(m1 - M), w2 = __expf(m2 - M);
    const float inv = 1.f / (w1 * l1 + w2 * l2);
    const float* o1 = Opart + (size_t)t0 * 4096 + q * 64 + dc;
    const float* o2 = Opart + (size_t)t1 * 4096 + q * 64 + dc;
    unsigned short* dst = Ob + ((size_t)b * SEQ + qt * 64 + q) * EMBED + h * HD + dc;
#pragma unroll
    for (int v = 0; v < 4; v++) {
        f32x4 a = *reinterpret_cast<const f32x4*>(o1 + 4 * v);
        f32x4 c = *reinterpret_cast<const f32x4*>(o2 + 4 * v);
        ushort4 u;
        u.x = f2bf((w1 * a[0] + w2 * c[0]) * inv);
        u.y = f2bf((w1 * a[1] + w2 * c[1]) * inv);
        u.z = f2bf((w1 * a[2] + w2 * c[2]) * inv);
        u.w = f2bf((w1 * a[3] + w2 * c[3]) * inv);
        *reinterpret_cast<ushort4*>(dst + 4 * v) = u;
    }
}

// ---------------- Kernel 3: output projection GEMM (m97-style) ----------------
// BM=64, BN=128, grid (64, 4). fp32 out + bias.
__global__ __launch_bounds__(256) void out_gemm(
    const unsigned short* __restrict__ Ao, const unsigned short* __restrict__ Wot,
    const float* __restrict__ bo, float* __restrict__ out)
{
    __shared__ __align__(16) unsigned short As[64 * 64];
    __shared__ __align__(16) unsigned short Bs[128 * 64];
    const int tid = threadIdx.x, lane = tid & 63, w = tid >> 6;
    const int fr = lane & 15, fg = lane >> 4;
    const int m0 = blockIdx.x * 64, n0 = blockIdx.y * 128;
    const int sr = lane >> 3;
    const int scs = ((lane & 7) * 16) ^ (sr << 4);

    const unsigned char* Ag = (const unsigned char*)Ao  + (size_t)(m0 + w * 8 + sr) * 1024 + scs;
    const unsigned char* Bg = (const unsigned char*)Wot + (size_t)(n0 + w * 8 + sr) * 1024 + scs;
    unsigned char* Asb = (unsigned char*)As;
    unsigned char* Bsb = (unsigned char*)Bs;

    f32x4 acc[2][4];
#pragma unroll
    for (int mt = 0; mt < 2; mt++)
#pragma unroll
        for (int nt = 0; nt < 4; nt++) acc[mt][nt] = (f32x4){0.f, 0.f, 0.f, 0.f};

    const int swz = (fr & 7) << 4;

    for (int k0 = 0; k0 < EMBED; k0 += 64) {
        async16(Asb + (w * 8) * 128,        Ag);
        async16(Asb + (32 + w * 8) * 128,   Ag + (size_t)32 * 1024);
        async16(Bsb + (w * 8) * 128,        Bg);
        async16(Bsb + (32 + w * 8) * 128,   Bg + (size_t)32 * 1024);
        async16(Bsb + (64 + w * 8) * 128,   Bg + (size_t)64 * 1024);
        async16(Bsb + (96 + w * 8) * 128,   Bg + (size_t)96 * 1024);
        Ag += 128; Bg += 128;
        __syncthreads();
#pragma unroll
        for (int h2 = 0; h2 < 2; h2++) {
            const int cb = (h2 * 64 + fg * 16) ^ swz;
            s16x8 a[2], bf[4];
#pragma unroll
            for (int mt = 0; mt < 2; mt++) {
                const int row = (w >> 1) * 32 + mt * 16 + fr;
                a[mt] = *reinterpret_cast<const s16x8*>(Asb + row * 128 + cb);
            }
#pragma unroll
            for (int nt = 0; nt < 4; nt++) {
                const int nrow = (w & 1) * 64 + nt * 16 + fr;
                bf[nt] = *reinterpret_cast<const s16x8*>(Bsb + nrow * 128 + cb);
            }
#pragma unroll
            for (int mt = 0; mt < 2; mt++)
#pragma unroll
                for (int nt = 0; nt < 4; nt++)
                    acc[mt][nt] = __builtin_amdgcn_mfma_f32_16x16x32_bf16(a[mt], bf[nt], acc[mt][nt], 0, 0, 0);
        }
        __syncthreads();
    }

    const int wc = w & 1, wr = w >> 1;
#pragma unroll
    for (int nt = 0; nt < 4; nt++) {
        const int col = n0 + wc * 64 + nt * 16 + fr;
        const float bb = bo[col];
#pragma unroll
        for (int mt = 0; mt < 2; mt++)
#pragma unroll
            for (int j = 0; j < 4; j++) {
                const int m = m0 + wr * 32 + mt * 16 + fg * 4 + j;
                out[(size_t)m * EMBED + col] = acc[mt][nt][j] + bb;
            }
    }
}

extern "C" void kernel_launch(void* const* d_in, const int* in_sizes, int n_in,
                              void* d_out, int out_size, void* d_ws, size_t ws_size,
                              hipStream_t stream) {
    const float* x    = (const float*)d_in[0];
    const float* bias = (const float*)d_in[1];
    const float* Wqkv = (const float*)d_in[2];
    const float* bqkv = (const float*)d_in[3];
    const float* Wo   = (const float*)d_in[4];
    const float* bo   = (const float*)d_in[5];
    float* out = (float*)d_out;

    const size_t perT = (size_t)BATCH * HEADS * SEQ * HD; // 2M elems
    unsigned short* Qb    = (unsigned short*)d_ws;
    unsigned short* Kb    = Qb + perT;
    unsigned short* Vt    = Kb + perT;
    unsigned short* Ob    = Vt + perT;
    unsigned short* Ab    = Ob + perT;
    unsigned short* Wqkvt = Ab + (size_t)BATCH * SEQ * IN_DIM;
    unsigned short* Wot   = Wqkvt + (size_t)N3 * IN_DIM;
    const size_t base_bytes = (size_t)(5 * perT + (size_t)N3 * IN_DIM + (size_t)EMBED * EMBED) * 2;
    float* Opart = (float*)((unsigned char*)d_ws + base_bytes);
    float* Mpart = Opart + (size_t)4 * HEADS * 32 * 4096;
    float* Lpart = Mpart + (size_t)4 * HEADS * 32 * 64;
    const size_t need = base_bytes + ((size_t)4 * HEADS * 32 * 4096 + (size_t)2 * 4 * HEADS * 32 * 64) * 4;
    const bool split = (ws_size >= need);

    prep_x<<<2048, 256, 0, stream>>>(x, Ab);
    transpose_w2<<<dim3(8, 32), 256, 0, stream>>>(Wqkv, Wo, Wqkvt, Wot);
    qkv_gemm<<<dim3(64, 12), 256, 0, stream>>>(Ab, Wqkvt, bqkv, Qb, Kb, Vt);
    if (split) {
        flash_attn<2><<<dim3(32, 8, 4), 256, 0, stream>>>(Qb, Kb, Vt, bias, Ob, Opart, Mpart, Lpart);
        combine<<<dim3(32, 8, 2), 256, 0, stream>>>(Opart, Mpart, Lpart, Ob);
    } else {
        flash_attn<1><<<dim3(32, 8, 2), 256, 0, stream>>>(Qb, Kb, Vt, bias, Ob, Opart, Mpart, Lpart);
    }
    out_gemm<<<dim3(64, 4), 256, 0, stream>>>(Ob, Wot, bo, out);
}